// Round 10
// baseline (294.424 us; speedup 1.0000x reference)
//
#include <hip/hip_runtime.h>
#include <hip/hip_cooperative_groups.h>
#include <math.h>
#include <stdint.h>

#define HF 64
#define WF 64
#define CC 512
#define NROI 256
#define NBINS 21   // 1 + 4 + 16

__device__ __forceinline__ float4 max4(float4 a, float4 b) {
    float4 r;
    r.x = fmaxf(a.x, b.x); r.y = fmaxf(a.y, b.y);
    r.z = fmaxf(a.z, b.z); r.w = fmaxf(a.w, b.w);
    return r;
}

__device__ __forceinline__ float4 ld4(const float* __restrict__ p, uint32_t byteoff) {
    return *(const float4*)((const char*)p + byteoff);
}

// Single cooperative dispatch:
//   Phase 1: build x-max pyramids Mx1 (win 2), Mx2 (win 4) into d_ws.
//            1024 blocks x 512 thr = 524288 threads = one float4 elem each.
//   grid.sync() (device-scope release/acquire -> ws visible cross-XCD)
//   Phase 2: round-8 RMQ query — block = (roi, quarter), wave = (jy, row-parity),
//            per (row,jx) ONE wave-load: lanes 0-31 window A (x1), lanes 32-63
//            window B (x2-2^k); k=1 for len 2-3, k=2 for len 4-8 (len is provably
//            in [2,8]). Overlapping pow2 windows cover [x1,x2) exactly; max is
//            idempotent -> bitwise exact. p4/p2/p1 via shfl + LDS (proven r0-r8).
// Residency: 8192 waves = 32/CU (cap); launch_bounds(512,8) caps VGPR at 64;
// LDS 26KB x 4 blk/CU = 104KB < 160KB. XCD swizzle proven r2-r8.
__global__ __launch_bounds__(512, 8) void roi_pool_coop(
    const float* __restrict__ img,
    const float* __restrict__ rois,
    float* __restrict__ mx1,
    float* __restrict__ mx2,
    float* __restrict__ out)
{
    __shared__ float ldsA[4][2][4][128];   // [jy][rp][jx][ch]
    __shared__ float ldsB[4][4][128];      // [jy][jx][ch]
    __shared__ float ldsC[2][2][128];      // [i2][j2][ch]

    // ---------- Phase 1: build ----------
    {
        const uint32_t i  = blockIdx.x * 512 + threadIdx.x;   // [0, 524288)
        const uint32_t c4 = i & 127;
        const uint32_t xx = (i >> 7) & 63;
        const uint32_t yy = i >> 13;
        const uint32_t rowb = yy * (64 * 128);

        const float4* imgv = (const float4*)img;
        const uint32_t xi1 = min(xx + 1, 63u);
        const uint32_t xi2 = min(xx + 2, 63u);
        const uint32_t xi3 = min(xx + 3, 63u);

        const float4 v0 = imgv[rowb + xx  * 128 + c4];
        const float4 v1 = imgv[rowb + xi1 * 128 + c4];
        const float4 v2 = imgv[rowb + xi2 * 128 + c4];
        const float4 v3 = imgv[rowb + xi3 * 128 + c4];

        const float4 m1 = max4(v0, v1);
        const float4 m2 = max4(m1, max4(v2, v3));
        ((float4*)mx1)[i] = m1;
        ((float4*)mx2)[i] = m2;
    }

    __threadfence();
    cooperative_groups::this_grid().sync();

    // ---------- Phase 2: query ----------
    const int bid  = blockIdx.x;                    // [0, 1024)
    const int q    = (bid & 7) >> 1;
    const int roi  = ((bid >> 3) << 1) | (bid & 1); // [0, 256) bijective
    const int tid  = threadIdx.x;
    const int wv   = tid >> 6;                      // 0..7
    const int jy   = wv >> 1;
    const int rp   = wv & 1;
    const int lane = tid & 63;
    const int half = lane >> 5;                     // window A/B select
    const int cl   = lane & 31;
    const int c0   = q * 128 + cl * 4;

    const float x = rois[roi * 4 + 0];
    const float y = rois[roi * 4 + 1];
    const float w = rois[roi * 4 + 2];
    const float h = rois[roi * 4 + 3];

    // Reference quirk: x-boundaries (W axis) use col_len = h/p; y-boundaries use w/p.
    const float clh = h * 0.25f;   // exact
    const float clw = w * 0.25f;   // exact

    int bx[5];
#pragma unroll
    for (int i = 0; i < 5; ++i)
        bx[i] = (int)rintf(__fadd_rn(x, __fmul_rn((float)i, clh)));

    const int y1 = (int)rintf(__fadd_rn(y, __fmul_rn((float)jy,       clw)));
    const int y2 = (int)rintf(__fadd_rn(y, __fmul_rn((float)(jy + 1), clw)));

    const uint32_t ROWB = WF * CC * 4;   // 131072
    const uint32_t PXB  = CC * 4;        // 2048
    const uint32_t cb   = (uint32_t)c0 * 4;

    const float* base[4];
    uint32_t coloff[4];
#pragma unroll
    for (int jx = 0; jx < 4; ++jx) {
        const int len = bx[jx + 1] - bx[jx];        // in [2, 8]
        const int big = (len >= 4);
        base[jx] = big ? mx2 : mx1;
        const int xa = bx[jx];
        const int xb = bx[jx + 1] - (big ? 4 : 2);
        coloff[jx] = (uint32_t)(half ? xb : xa) * PXB + cb;
    }

    float4 acc[4];
#pragma unroll
    for (int jx = 0; jx < 4; ++jx) {
        acc[jx].x = -INFINITY; acc[jx].y = -INFINITY;
        acc[jx].z = -INFINITY; acc[jx].w = -INFINITY;
    }

    for (int r = y1 + rp; r < y2; r += 2) {
        const uint32_t ro = (uint32_t)r * ROWB;
        acc[0] = max4(acc[0], ld4(base[0], ro + coloff[0]));
        acc[1] = max4(acc[1], ld4(base[1], ro + coloff[1]));
        acc[2] = max4(acc[2], ld4(base[2], ro + coloff[2]));
        acc[3] = max4(acc[3], ld4(base[3], ro + coloff[3]));
    }

#pragma unroll
    for (int jx = 0; jx < 4; ++jx) {
        float4 a = acc[jx];
        a.x = fmaxf(a.x, __shfl_xor(a.x, 32));
        a.y = fmaxf(a.y, __shfl_xor(a.y, 32));
        a.z = fmaxf(a.z, __shfl_xor(a.z, 32));
        a.w = fmaxf(a.w, __shfl_xor(a.w, 32));
        acc[jx] = a;
    }

    if (half == 0) {
#pragma unroll
        for (int jx = 0; jx < 4; ++jx)
            *(float4*)(&ldsA[jy][rp][jx][cl * 4]) = acc[jx];
    }
    __syncthreads();

    float* outr = out + (size_t)roi * (NBINS * CC) + c0;

    // p4: row-parity combine
    if (rp == 0 && half == 0) {
#pragma unroll
        for (int jx = 0; jx < 4; ++jx) {
            const float4 m = max4(*(const float4*)(&ldsA[jy][0][jx][cl * 4]),
                                  *(const float4*)(&ldsA[jy][1][jx][cl * 4]));
            *(float4*)(outr + (size_t)(5 + jx * 4 + jy) * CC) = m;
            *(float4*)(&ldsB[jy][jx][cl * 4]) = m;
        }
    }
    __syncthreads();

    // p2
    if (wv < 4 && half == 0) {
        const int i2 = wv >> 1;
        const int j2 = wv & 1;
        const float4 f00 = *(const float4*)(&ldsB[2*j2  ][2*i2  ][cl * 4]);
        const float4 f01 = *(const float4*)(&ldsB[2*j2  ][2*i2+1][cl * 4]);
        const float4 f10 = *(const float4*)(&ldsB[2*j2+1][2*i2  ][cl * 4]);
        const float4 f11 = *(const float4*)(&ldsB[2*j2+1][2*i2+1][cl * 4]);
        const float4 a = max4(max4(f00, f01), max4(f10, f11));
        *(float4*)(outr + (size_t)(1 + i2 * 2 + j2) * CC) = a;
        *(float4*)(&ldsC[i2][j2][cl * 4]) = a;
    }
    __syncthreads();

    // p1
    if (wv == 0 && half == 0) {
        const float4 a00 = *(const float4*)(&ldsC[0][0][cl * 4]);
        const float4 a01 = *(const float4*)(&ldsC[0][1][cl * 4]);
        const float4 a10 = *(const float4*)(&ldsC[1][0][cl * 4]);
        const float4 a11 = *(const float4*)(&ldsC[1][1][cl * 4]);
        *(float4*)(outr) = max4(max4(a00, a01), max4(a10, a11));
    }
}

// ---------------- Fallback (round-7 kernel, proven 21.5 us) ----------------
__global__ __launch_bounds__(512) void roi_pool_fused_fb(
    const float* __restrict__ img,
    const float* __restrict__ rois,
    float* __restrict__ out)
{
    __shared__ float ldsA[4][2][4][128];
    __shared__ float ldsB[4][4][128];
    __shared__ float ldsC[2][2][128];

    const int bid  = blockIdx.x;
    const int q    = (bid & 7) >> 1;
    const int roi  = ((bid >> 3) << 1) | (bid & 1);
    const int tid  = threadIdx.x;
    const int wv   = tid >> 6;
    const int jy   = wv >> 1;
    const int rp   = wv & 1;
    const int lane = tid & 63;
    const int half = lane >> 5;
    const int cl   = lane & 31;
    const int c0   = q * 128 + cl * 4;

    const float x = rois[roi * 4 + 0];
    const float y = rois[roi * 4 + 1];
    const float w = rois[roi * 4 + 2];
    const float h = rois[roi * 4 + 3];
    const float clh = h * 0.25f;
    const float clw = w * 0.25f;

    int bx[5];
#pragma unroll
    for (int i = 0; i < 5; ++i)
        bx[i] = (int)rintf(__fadd_rn(x, __fmul_rn((float)i, clh)));

    const int y1 = (int)rintf(__fadd_rn(y, __fmul_rn((float)jy,       clw)));
    const int y2 = (int)rintf(__fadd_rn(y, __fmul_rn((float)(jy + 1), clw)));

    const int w01 = max(bx[1] - bx[0], bx[2] - bx[1]);
    const int w23 = max(bx[3] - bx[2], bx[4] - bx[3]);
    const int K   = (max(w01, w23) + 1) >> 1;

    float4 acc[4];
#pragma unroll
    for (int jx = 0; jx < 4; ++jx) {
        acc[jx].x = -INFINITY; acc[jx].y = -INFINITY;
        acc[jx].z = -INFINITY; acc[jx].w = -INFINITY;
    }

    const uint32_t ROWB = WF * CC * 4;
    const uint32_t PXB  = CC * 4;
    const uint32_t cb   = (uint32_t)c0 * 4;

    for (int r = y1 + rp; r < y2; r += 2) {
        const uint32_t ro = cb + (uint32_t)r * ROWB;
        for (int k = 0; k < K; ++k) {
            const int cc2 = 2 * k + half;
#pragma unroll
            for (int jx = 0; jx < 4; ++jx) {
                const int col = min(bx[jx] + cc2, bx[jx + 1] - 1);
                acc[jx] = max4(acc[jx], ld4(img, ro + (uint32_t)col * PXB));
            }
        }
    }

#pragma unroll
    for (int jx = 0; jx < 4; ++jx) {
        float4 a = acc[jx];
        a.x = fmaxf(a.x, __shfl_xor(a.x, 32));
        a.y = fmaxf(a.y, __shfl_xor(a.y, 32));
        a.z = fmaxf(a.z, __shfl_xor(a.z, 32));
        a.w = fmaxf(a.w, __shfl_xor(a.w, 32));
        acc[jx] = a;
    }

    if (half == 0) {
#pragma unroll
        for (int jx = 0; jx < 4; ++jx)
            *(float4*)(&ldsA[jy][rp][jx][cl * 4]) = acc[jx];
    }
    __syncthreads();

    float* outr = out + (size_t)roi * (NBINS * CC) + c0;

    if (rp == 0 && half == 0) {
#pragma unroll
        for (int jx = 0; jx < 4; ++jx) {
            const float4 m = max4(*(const float4*)(&ldsA[jy][0][jx][cl * 4]),
                                  *(const float4*)(&ldsA[jy][1][jx][cl * 4]));
            *(float4*)(outr + (size_t)(5 + jx * 4 + jy) * CC) = m;
            *(float4*)(&ldsB[jy][jx][cl * 4]) = m;
        }
    }
    __syncthreads();

    if (wv < 4 && half == 0) {
        const int i2 = wv >> 1;
        const int j2 = wv & 1;
        const float4 f00 = *(const float4*)(&ldsB[2*j2  ][2*i2  ][cl * 4]);
        const float4 f01 = *(const float4*)(&ldsB[2*j2  ][2*i2+1][cl * 4]);
        const float4 f10 = *(const float4*)(&ldsB[2*j2+1][2*i2  ][cl * 4]);
        const float4 f11 = *(const float4*)(&ldsB[2*j2+1][2*i2+1][cl * 4]);
        const float4 a = max4(max4(f00, f01), max4(f10, f11));
        *(float4*)(outr + (size_t)(1 + i2 * 2 + j2) * CC) = a;
        *(float4*)(&ldsC[i2][j2][cl * 4]) = a;
    }
    __syncthreads();

    if (wv == 0 && half == 0) {
        const float4 a00 = *(const float4*)(&ldsC[0][0][cl * 4]);
        const float4 a01 = *(const float4*)(&ldsC[0][1][cl * 4]);
        const float4 a10 = *(const float4*)(&ldsC[1][0][cl * 4]);
        const float4 a11 = *(const float4*)(&ldsC[1][1][cl * 4]);
        *(float4*)(outr) = max4(max4(a00, a01), max4(a10, a11));
    }
}

extern "C" void kernel_launch(void* const* d_in, const int* in_sizes, int n_in,
                              void* d_out, int out_size, void* d_ws, size_t ws_size,
                              hipStream_t stream) {
    const float* img  = (const float*)d_in[0];   // (1,64,64,512) fp32
    const float* rois = (const float*)d_in[1];   // (1,256,4) fp32
    float* out = (float*)d_out;                  // (1,256,21*512) fp32

    const size_t PYR = (size_t)HF * WF * CC;     // 2M floats = 8 MB

    bool done = false;
    if (ws_size >= 2 * PYR * sizeof(float)) {
        float* mx1 = (float*)d_ws;
        float* mx2 = mx1 + PYR;
        void* kargs[] = { (void*)&img, (void*)&rois, (void*)&mx1, (void*)&mx2, (void*)&out };
        hipError_t err = hipLaunchCooperativeKernel(
            (const void*)roi_pool_coop, dim3(NROI * 4), dim3(512), kargs, 0, stream);
        done = (err == hipSuccess);
    }
    if (!done) {
        roi_pool_fused_fb<<<dim3(NROI * 4), dim3(512), 0, stream>>>(img, rois, out);
    }
}

// Round 11
// 21.128 us; speedup vs baseline: 13.9353x; 13.9353x over previous
//
#include <hip/hip_runtime.h>
#include <math.h>
#include <stdint.h>

#define HF 64
#define WF 64
#define CC 512
#define NROI 256
#define NBINS 21   // 1 + 4 + 16

// FINAL (reverted to round-6 best: 21.20 us measured).
// Session findings:
//  - p1/p2 bins are bitwise-derivable from p4 bins (exact fp32 boundary identity).
//  - XCD channel-quarter sharding (+31%), float4 lanes, fused single dispatch.
//  - 21.2 us is a harness replay floor: invariant under structure/MLP/traffic/
//    dispatch-count changes (rounds 4-9). grid.sync() costs ~270 us — never use.

__device__ __forceinline__ float4 max4(float4 a, float4 b) {
    float4 r;
    r.x = fmaxf(a.x, b.x); r.y = fmaxf(a.y, b.y);
    r.z = fmaxf(a.z, b.z); r.w = fmaxf(a.w, b.w);
    return r;
}

__device__ __forceinline__ float4 ld4(const float* __restrict__ img, uint32_t byteoff) {
    return *(const float4*)((const char*)img + byteoff);
}

// Fused kernel: block = (roi, channel-quarter of 128 ch), 1024 threads = 16 waves.
//   wave wv -> fine bin (jy = wv>>2, jx = wv&3).
//   lanes: cl = lane&31 -> 4 channels (float4), half = lane>>5 -> pixel-column parity.
// Inner loop: branch-free via clamped duplicate loads (min(idx,last) — duplicates
// are exact for max), rows x2 + cols x4 unroll -> 4 independent acc chains.
// 32-bit byte offsets + uniform img base -> saddr-form global_load_dwordx4.
// p2/p1 derived block-locally via LDS (exact; boundary arith bitwise = reference).
// XCD swizzle (proven r2-r9): bid&7 -> XCD, quarter q = (bid&7)>>1 -> XCD pair {2q,2q+1}.
__global__ __launch_bounds__(1024) void roi_pool_fused(
    const float* __restrict__ img,
    const float* __restrict__ rois,
    float* __restrict__ out)
{
    __shared__ float fineLds[4][4][128];   // [jy][jx][ch-in-quarter]
    __shared__ float p2Lds[2][2][128];     // [i2][j2][ch-in-quarter]

    const int bid  = blockIdx.x;                    // [0, 1024)
    const int q    = (bid & 7) >> 1;                // channel quarter
    const int roi  = ((bid >> 3) << 1) | (bid & 1); // [0, 256) bijective
    const int tid  = threadIdx.x;
    const int wv   = tid >> 6;                      // wave id = fine bin
    const int jy   = wv >> 2;                       // y fine-bin (H axis)
    const int jx   = wv & 3;                        // x fine-bin (W axis)
    const int lane = tid & 63;
    const int half = lane >> 5;                     // pixel-column parity
    const int cl   = lane & 31;                     // channel lane
    const int c0   = q * 128 + cl * 4;

    const float x = rois[roi * 4 + 0];
    const float y = rois[roi * 4 + 1];
    const float w = rois[roi * 4 + 2];
    const float h = rois[roi * 4 + 3];

    // Reference quirk: x-boundaries (W axis) use col_len = h/p; y-boundaries use w/p.
    const float clh = h * 0.25f;   // exact
    const float clw = w * 0.25f;   // exact

    const int x1 = (int)rintf(__fadd_rn(x, __fmul_rn((float)jx,       clh)));
    const int x2 = (int)rintf(__fadd_rn(x, __fmul_rn((float)(jx + 1), clh)));
    const int y1 = (int)rintf(__fadd_rn(y, __fmul_rn((float)jy,       clw)));
    const int y2 = (int)rintf(__fadd_rn(y, __fmul_rn((float)(jy + 1), clw)));

    const int ylast = y2 - 1;
    const int xlast = x2 - 1;

    float4 acc0, acc1, acc2, acc3;
    acc0.x = -INFINITY; acc0.y = -INFINITY; acc0.z = -INFINITY; acc0.w = -INFINITY;
    acc1 = acc0; acc2 = acc0; acc3 = acc0;

    const uint32_t ROWB = WF * CC * 4;   // 131072
    const uint32_t PXB  = CC * 4;        // 2048
    const uint32_t cb   = (uint32_t)c0 * 4;

    for (int hh = y1; hh < y2; hh += 2) {
        const int h1 = min(hh + 1, ylast);
        const uint32_t ro0 = cb + (uint32_t)hh * ROWB;
        const uint32_t ro1 = cb + (uint32_t)h1 * ROWB;
        for (int cc = x1; cc < x2; cc += 4) {
            const uint32_t w0 = (uint32_t)min(cc + half,     xlast) * PXB;
            const uint32_t w1 = (uint32_t)min(cc + 2 + half, xlast) * PXB;
            const float4 v0 = ld4(img, ro0 + w0);
            const float4 v1 = ld4(img, ro1 + w0);
            const float4 v2 = ld4(img, ro0 + w1);
            const float4 v3 = ld4(img, ro1 + w1);
            acc0 = max4(acc0, v0);
            acc1 = max4(acc1, v1);
            acc2 = max4(acc2, v2);
            acc3 = max4(acc3, v3);
        }
    }
    float4 acc = max4(max4(acc0, acc1), max4(acc2, acc3));

    // combine the two pixel-parity halves (same channels, disjoint pixel sets)
    acc.x = fmaxf(acc.x, __shfl_xor(acc.x, 32));
    acc.y = fmaxf(acc.y, __shfl_xor(acc.y, 32));
    acc.z = fmaxf(acc.z, __shfl_xor(acc.z, 32));
    acc.w = fmaxf(acc.w, __shfl_xor(acc.w, 32));

    float* outr = out + (size_t)roi * (NBINS * CC) + c0;

    if (half == 0) {
        *(float4*)(outr + (size_t)(5 + jx * 4 + jy) * CC) = acc;
        *(float4*)(&fineLds[jy][jx][cl * 4]) = acc;
    }
    __syncthreads();

    // p2: waves 0..3 -> coarse bin (i2 = wv>>1, j2 = wv&1)
    if (wv < 4 && half == 0) {
        const int i2 = wv >> 1;
        const int j2 = wv & 1;
        const float4 f00 = *(const float4*)(&fineLds[2*j2  ][2*i2  ][cl * 4]);
        const float4 f01 = *(const float4*)(&fineLds[2*j2  ][2*i2+1][cl * 4]);
        const float4 f10 = *(const float4*)(&fineLds[2*j2+1][2*i2  ][cl * 4]);
        const float4 f11 = *(const float4*)(&fineLds[2*j2+1][2*i2+1][cl * 4]);
        const float4 a = max4(max4(f00, f01), max4(f10, f11));
        *(float4*)(outr + (size_t)(1 + i2 * 2 + j2) * CC) = a;
        *(float4*)(&p2Lds[i2][j2][cl * 4]) = a;
    }
    __syncthreads();

    // p1: wave 0
    if (wv == 0 && half == 0) {
        const float4 a00 = *(const float4*)(&p2Lds[0][0][cl * 4]);
        const float4 a01 = *(const float4*)(&p2Lds[0][1][cl * 4]);
        const float4 a10 = *(const float4*)(&p2Lds[1][0][cl * 4]);
        const float4 a11 = *(const float4*)(&p2Lds[1][1][cl * 4]);
        *(float4*)(outr) = max4(max4(a00, a01), max4(a10, a11));
    }
}

extern "C" void kernel_launch(void* const* d_in, const int* in_sizes, int n_in,
                              void* d_out, int out_size, void* d_ws, size_t ws_size,
                              hipStream_t stream) {
    const float* img  = (const float*)d_in[0];   // (1,64,64,512) fp32
    const float* rois = (const float*)d_in[1];   // (1,256,4) fp32
    float* out = (float*)d_out;                  // (1,256,21*512) fp32

    dim3 grid(NROI * 4);     // (roi, quarter) = 1024 blocks
    dim3 block(1024);        // 16 waves = 16 fine bins
    roi_pool_fused<<<grid, block, 0, stream>>>(img, rois, out);
}